// Round 5
// baseline (1948.590 us; speedup 1.0000x reference)
//
#include <hip/hip_runtime.h>
#include <cstdint>

typedef unsigned short u16;
typedef __attribute__((ext_vector_type(4))) float f32x4;
typedef __attribute__((ext_vector_type(8))) short bf16x8;   // 8 bf16 in 4 VGPRs
typedef __attribute__((ext_vector_type(4))) u16 u16x4;

constexpr int NB = 1024;   // batch
constexpr int NT = 200;    // time
constexpr int ND = 128;    // input dim
constexpr int NU = 128;    // units
constexpr int NG = 512;    // 4*U gates
constexpr int ROWS = 16;   // batch rows per block (MFMA M)
constexpr int AK = 512;    // A-tile k extent: [xhi|xlo|hhi|hlo] x 128
constexpr int ABUF = ROWS * AK;           // 8192 u16 per buffer
constexpr int LDS_A_ELEMS  = 2 * ABUF;    // double-buffered: 16384 u16 = 32 KiB
constexpr int LDS_WK_ELEMS = NG * ND;     // 65536 u16 = 128 KiB (Wk_lo, [col][k])

__device__ __forceinline__ u16 f2bf(float x) {
    uint32_t u = __builtin_bit_cast(uint32_t, x);
    u = (u + 0x7fffu + ((u >> 16) & 1u)) >> 16;   // RNE
    return (u16)u;
}
__device__ __forceinline__ float bf2f(u16 b) {
    uint32_t u = ((uint32_t)b) << 16;
    return __builtin_bit_cast(float, u);
}
__device__ __forceinline__ float sigm(float x) {
    return __builtin_amdgcn_rcpf(1.f + __expf(-x));
}
__device__ __forceinline__ float tanh_fast(float x) {
    float e = __expf(-2.f * fabsf(x));
    float t = (1.f - e) * __builtin_amdgcn_rcpf(1.f + e);
    return copysignf(t, x);
}

// Light workgroup barrier: orders LDS only (lgkmcnt(0)), leaves global
// loads/stores in flight (no vmcnt drain — the per-step killer in r2/r3).
__device__ __forceinline__ void lds_barrier() {
    asm volatile("s_waitcnt lgkmcnt(0)" ::: "memory");
    __builtin_amdgcn_s_barrier();
    __builtin_amdgcn_sched_barrier(0);
    asm volatile("" ::: "memory");
}

// One LSTM layer scan for 16 batch rows. WKL: include the x_hi * Wk_lo
// correction (layer 1, whose input has nonzero temporal mean -> coherent
// weight-rounding error; layer 0's x is zero-mean -> incoherent, skip).
template<bool WKL>
__device__ __forceinline__ void run_layer(
    const float* __restrict__ Wk, const float* __restrict__ Wr,
    const float* __restrict__ Bv,
    const float* __restrict__ src, float* __restrict__ dst,
    u16* A, u16* WKLO, const int dir, const int base_b,
    const int tid, const int q, const int cl, const int uu,
    const int sr, const int sc)
{
    __syncthreads();   // heavy: prior layer's LDS reads done, global stores visible

    // ---- resident weight fragments (B-side): Wk_hi, Wr_hi, Wr_lo
    bf16x8 wkh[4][4], wrh[4][4], wrl[4][4];
    #pragma unroll
    for (int g = 0; g < 4; ++g) {
        const int col = g * NU + uu;
        #pragma unroll
        for (int s = 0; s < 4; ++s) {
            bf16x8 fa, fh, fl;
            #pragma unroll
            for (int j = 0; j < 8; ++j) {
                const int k = s * 32 + q * 8 + j;
                fa[j] = (short)f2bf(Wk[k * NG + col]);
                const float w = Wr[k * NG + col];
                const u16 hi = f2bf(w);
                fh[j] = (short)hi;
                fl[j] = (short)f2bf(w - bf2f(hi));
            }
            wkh[g][s] = fa; wrh[g][s] = fh; wrl[g][s] = fl;
        }
    }
    float bias[4];
    #pragma unroll
    for (int g = 0; g < 4; ++g) bias[g] = Bv[g * NU + uu];

    if (WKL) {   // fill Wk_lo into LDS (transposed [col][k], swizzled)
        for (int idx = tid; idx < LDS_WK_ELEMS; idx += 512) {
            const int col = idx & (NG - 1);
            const int k   = idx >> 9;
            const float w = Wk[k * NG + col];
            const float lo = w - bf2f(f2bf(w));
            WKLO[(uint32_t)(col * 256 + ((2 * k) ^ ((col & 15) << 4))) >> 1] = f2bf(lo);
        }
    }
    for (int i = tid; i < LDS_A_ELEMS; i += 512) A[i] = 0;   // h planes must be 0
    f32x4 cc = {0.f, 0.f, 0.f, 0.f};

    const size_t srow = (size_t)(base_b + sr) * (NT * NU) + sc;
    const uint32_t stg = (uint32_t)(sr * 1024 + ((2 * sc) ^ ((sr & 15) << 4))) >> 1;

    // r4 bug fix: zeroing (all threads, whole A) must be ordered BEFORE the
    // prologue staging writes — otherwise another thread's zero can land on
    // top of our staged x0 (absmax 0.268 in r4).
    __syncthreads();

    // prologue: stage x_{t0} into buffer 0
    {
        const float4 v = *(const float4*)&src[srow + (size_t)(dir ? NT - 1 : 0) * NU];
        const float vv[4] = {v.x, v.y, v.z, v.w};
        u16x4 hi4, lo4;
        #pragma unroll
        for (int e = 0; e < 4; ++e) {
            const u16 h = f2bf(vv[e]);
            hi4[e] = h;
            lo4[e] = f2bf(vv[e] - bf2f(h));
        }
        *(u16x4*)&A[stg]       = hi4;
        *(u16x4*)&A[stg + 128] = lo4;
    }
    __syncthreads();   // staging + WKLO visible

    int p = 0;
    for (int step = 0; step < NT; ++step) {
        const int t = dir ? (NT - 1 - step) : step;

        // ---- prefetch x_{t+1} now; used ~2k cycles later at staging
        float4 nxt;
        const bool have_nxt = (step + 1 < NT);
        if (have_nxt) {
            const int tn = dir ? (NT - 2 - step) : (step + 1);
            nxt = *(const float4*)&src[srow + (size_t)tn * NU];
        }

        const u16* Ard = A + p * ABUF;
        u16*       Awr = A + (p ^ 1) * ABUF;

        f32x4 accx[4], acch[4];   // x-side (carries bias) and h-side chains
        #pragma unroll
        for (int g = 0; g < 4; ++g) {
            accx[g] = (f32x4){bias[g], bias[g], bias[g], bias[g]};
            acch[g] = (f32x4){0.f, 0.f, 0.f, 0.f};
        }

        #pragma unroll
        for (int s = 0; s < 4; ++s) {
            const uint32_t ab =
                (uint32_t)(cl * 1024 + ((s * 64 + q * 16) ^ ((cl & 15) << 4)));
            const bf16x8 axh = *(const bf16x8*)&Ard[(ab >> 1)];
            const bf16x8 axl = *(const bf16x8*)&Ard[(ab >> 1) + 128];
            const bf16x8 ahh = *(const bf16x8*)&Ard[(ab >> 1) + 256];
            const bf16x8 ahl = *(const bf16x8*)&Ard[(ab >> 1) + 384];
            #pragma unroll
            for (int g = 0; g < 4; ++g) {
                accx[g] = __builtin_amdgcn_mfma_f32_16x16x32_bf16(axh, wkh[g][s], accx[g], 0, 0, 0);
                accx[g] = __builtin_amdgcn_mfma_f32_16x16x32_bf16(axl, wkh[g][s], accx[g], 0, 0, 0);
                if (WKL) {
                    const int col = g * NU + uu;
                    const bf16x8 wkl = *(const bf16x8*)
                        &WKLO[(uint32_t)(col * 256 + ((s * 64 + q * 16) ^ ((col & 15) << 4))) >> 1];
                    accx[g] = __builtin_amdgcn_mfma_f32_16x16x32_bf16(axh, wkl, accx[g], 0, 0, 0);
                }
                acch[g] = __builtin_amdgcn_mfma_f32_16x16x32_bf16(ahh, wrh[g][s], acch[g], 0, 0, 0);
                acch[g] = __builtin_amdgcn_mfma_f32_16x16x32_bf16(ahl, wrh[g][s], acch[g], 0, 0, 0);
                acch[g] = __builtin_amdgcn_mfma_f32_16x16x32_bf16(ahh, wrl[g][s], acch[g], 0, 0, 0);
            }
        }

        // gates + state; C/D layout: col = lane&15 (unit), row = q*4+j (batch row)
        #pragma unroll
        for (int j = 0; j < 4; ++j) {
            const int r = q * 4 + j;
            const float gi = sigm(accx[0][j] + acch[0][j]);
            const float gf = sigm(accx[1][j] + acch[1][j]);
            const float gg = tanh_fast(accx[2][j] + acch[2][j]);
            const float go = sigm(accx[3][j] + acch[3][j]);
            const float cn = gf * cc[j] + gi * gg;
            cc[j] = cn;
            const float h = go * tanh_fast(cn);
            const u16 hh = f2bf(h);
            const u16 hl = f2bf(h - bf2f(hh));
            const uint32_t hb = (uint32_t)(r * 1024 + ((2 * uu) ^ ((r & 15) << 4)));
            Awr[(hb >> 1) + 256] = hh;   // h_hi plane of the NEXT-step buffer
            Awr[(hb >> 1) + 384] = hl;   // h_lo plane
            dst[(size_t)(base_b + r) * (NT * NU) + (size_t)t * NU + uu] = h;
        }

        // stage x_{t+1} into the next-step buffer
        if (have_nxt) {
            const float vv[4] = {nxt.x, nxt.y, nxt.z, nxt.w};
            u16x4 hi4, lo4;
            #pragma unroll
            for (int e = 0; e < 4; ++e) {
                const u16 h = f2bf(vv[e]);
                hi4[e] = h;
                lo4[e] = f2bf(vv[e] - bf2f(h));
            }
            *(u16x4*)&Awr[stg]       = hi4;
            *(u16x4*)&Awr[stg + 128] = lo4;
        }

        lds_barrier();   // LDS-only: h/x writes visible; globals stay in flight
        p ^= 1;
    }
}

__global__ __launch_bounds__(512, 2)
void lstm_scan(const float* __restrict__ x,
               const float* __restrict__ fwk, const float* __restrict__ fwrk,
               const float* __restrict__ fwb,
               const float* __restrict__ bwk, const float* __restrict__ bwrk,
               const float* __restrict__ bwb,
               float* __restrict__ buf_fw, float* __restrict__ buf_bw) {
    extern __shared__ __align__(16) u16 smem[];
    u16* A    = smem;                 // 2 x [16][512] bf16, XOR-swizzled rows
    u16* WKLO = smem + LDS_A_ELEMS;   // [512 col][128 k] bf16, XOR-swizzled

    const int tid  = threadIdx.x;
    const int lane = tid & 63;
    const int wv   = tid >> 6;          // wave 0..7
    const int dir  = blockIdx.y;        // 0 = fw, 1 = bw
    const int base_b = blockIdx.x * ROWS;

    const float* kp = dir ? bwk  : fwk;
    const float* rp = dir ? bwrk : fwrk;
    const float* bp = dir ? bwb  : fwb;
    float* buf = dir ? buf_bw : buf_fw;

    const int q  = lane >> 4;           // k-group 0..3
    const int cl = lane & 15;           // A-row / B-col within tile
    const int uu = (wv << 4) + cl;      // unit 0..127 owned by this lane

    const int sr = tid >> 5;            // staging row 0..15
    const int sc = (tid & 31) << 2;     // staging col 0..124

    // layer 0: input x, no Wk_lo correction (zero-mean input -> incoherent err)
    run_layer<false>(kp, rp, bp, x, buf, A, WKLO, dir, base_b,
                     tid, q, cl, uu, sr, sc);
    // layer 1: input = layer-0 h sequence (nonzero mean -> keep Wk_lo), in-place
    run_layer<true>(kp + ND * NG, rp + NU * NG, bp + NG, buf, buf, A, WKLO,
                    dir, base_b, tid, q, cl, uu, sr, sc);
}

// ---- merge: out = 0.5*(fw + bw) ---------------------------------------------
__global__ void merge_out(const float* __restrict__ a, const float* __restrict__ b,
                          float* __restrict__ o, int nvec) {
    int i = blockIdx.x * blockDim.x + threadIdx.x;
    const int st = gridDim.x * blockDim.x;
    for (; i < nvec; i += st) {
        const float4 va = ((const float4*)a)[i];
        const float4 vb = ((const float4*)b)[i];
        float4 r;
        r.x = 0.5f * (va.x + vb.x);
        r.y = 0.5f * (va.y + vb.y);
        r.z = 0.5f * (va.z + vb.z);
        r.w = 0.5f * (va.w + vb.w);
        ((float4*)o)[i] = r;
    }
}

extern "C" void kernel_launch(void* const* d_in, const int* in_sizes, int n_in,
                              void* d_out, int out_size, void* d_ws, size_t ws_size,
                              hipStream_t stream) {
    const float* x    = (const float*)d_in[0];
    const float* fwk  = (const float*)d_in[1];
    const float* fwrk = (const float*)d_in[2];
    const float* fwb  = (const float*)d_in[3];
    const float* bwk  = (const float*)d_in[4];
    const float* bwrk = (const float*)d_in[5];
    const float* bwb  = (const float*)d_in[6];
    float* out = (float*)d_out;

    const size_t seq = (size_t)NB * NT * NU;     // 26,214,400 elements
    float* buf_fw = (float*)d_ws;                // fw h-sequence fp32 (l0 then l1 in-place)
    float* buf_bw = buf_fw + seq;                // bw h-sequence fp32

    const size_t lds_bytes = (size_t)(LDS_A_ELEMS + LDS_WK_ELEMS) * sizeof(u16); // 163840
    (void)hipFuncSetAttribute((const void*)lstm_scan,
                              hipFuncAttributeMaxDynamicSharedMemorySize,
                              (int)lds_bytes);

    lstm_scan<<<dim3(NB / ROWS, 2), 512, lds_bytes, stream>>>(
        x, fwk, fwrk, fwb, bwk, bwrk, bwb, buf_fw, buf_bw);

    const int nvec = (int)(seq / 4);
    merge_out<<<2048, 256, 0, stream>>>(buf_fw, buf_bw, out, nvec);
}